// Round 1
// baseline (12695.658 us; speedup 1.0000x reference)
//
#include <hip/hip_runtime.h>

#define A_ 8
#define B_ 64
#define S_ 128
#define E_ 512
#define H_ 512
#define KT 128

__device__ __forceinline__ float sigm(float v)   { return 1.f / (1.f + __expf(-v)); }
__device__ __forceinline__ float tanh_f(float v) { return 2.f / (1.f + __expf(-2.f * v)) - 1.f; }

// One GRU time-step. Grid: (16 n-slices, 2 b-halves, 8 a). 256 threads.
// Each block: 32 b-rows x 32 n-cols. Each thread: 4 b-rows x 1 n-col.
__global__ __launch_bounds__(256) void gru_step(
    const float* __restrict__ x,
    const float* __restrict__ wri, const float* __restrict__ wzi, const float* __restrict__ wni,
    const float* __restrict__ wrh, const float* __restrict__ wzh, const float* __restrict__ wnh,
    const float* __restrict__ bri, const float* __restrict__ bzi, const float* __restrict__ bni,
    const float* __restrict__ brh, const float* __restrict__ bzh, const float* __restrict__ bnh,
    const float* __restrict__ hprev, float* __restrict__ hnext,
    float* __restrict__ out, float* __restrict__ hlast, int s)
{
  const int jn  = blockIdx.x;   // 0..15  n-slice
  const int jb  = blockIdx.y;   // 0..1   b-half
  const int a   = blockIdx.z;   // 0..7
  const int tid = threadIdx.x;
  const int tn  = tid & 31;
  const int bg  = tid >> 5;     // 0..7
  const int n   = jn * 32 + tn;
  const int b0  = jb * 32;

  __shared__ float xt[32][KT];
  __shared__ float ht[32][KT];

  float racc[4]  = {0.f, 0.f, 0.f, 0.f};
  float zacc[4]  = {0.f, 0.f, 0.f, 0.f};
  float xnacc[4] = {0.f, 0.f, 0.f, 0.f};
  float hnacc[4] = {0.f, 0.f, 0.f, 0.f};

  // ---- e-part: x[a, b, s, :] . W_in[:, n] for 3 gates ----
  for (int kt0 = 0; kt0 < E_; kt0 += KT) {
    __syncthreads();
    #pragma unroll
    for (int t = 0; t < 4; ++t) {
      int idx = tid + t * 256;          // 0..1023 float4 slots
      int row = idx >> 5;               // 32 float4 per row
      int c4  = idx & 31;
      const float4* src = reinterpret_cast<const float4*>(
          x + (((size_t)(a * B_ + b0 + row) * S_ + s) * E_ + kt0)) + c4;
      reinterpret_cast<float4*>(&xt[row][0])[c4] = *src;
    }
    __syncthreads();
    size_t wb = (size_t)(a * E_ + kt0) * H_ + n;
    #pragma unroll 4
    for (int k = 0; k < KT; ++k) {
      float wr = wri[wb + (size_t)k * H_];
      float wz = wzi[wb + (size_t)k * H_];
      float wn = wni[wb + (size_t)k * H_];
      #pragma unroll
      for (int i = 0; i < 4; ++i) {
        float xv = xt[bg * 4 + i][k];
        racc[i]  = fmaf(xv, wr, racc[i]);
        zacc[i]  = fmaf(xv, wz, zacc[i]);
        xnacc[i] = fmaf(xv, wn, xnacc[i]);
      }
    }
  }

  // ---- h-part: h[a, b, :] . W_h[:, n] for 3 gates ----
  for (int kt0 = 0; kt0 < H_; kt0 += KT) {
    __syncthreads();
    #pragma unroll
    for (int t = 0; t < 4; ++t) {
      int idx = tid + t * 256;
      int row = idx >> 5;
      int c4  = idx & 31;
      const float4* src = reinterpret_cast<const float4*>(
          hprev + ((size_t)(a * B_ + b0 + row) * H_ + kt0)) + c4;
      reinterpret_cast<float4*>(&ht[row][0])[c4] = *src;
    }
    __syncthreads();
    size_t wb = (size_t)(a * H_ + kt0) * H_ + n;
    #pragma unroll 4
    for (int k = 0; k < KT; ++k) {
      float wr = wrh[wb + (size_t)k * H_];
      float wz = wzh[wb + (size_t)k * H_];
      float wn = wnh[wb + (size_t)k * H_];
      #pragma unroll
      for (int i = 0; i < 4; ++i) {
        float hv = ht[bg * 4 + i][k];
        racc[i]  = fmaf(hv, wr, racc[i]);
        zacc[i]  = fmaf(hv, wz, zacc[i]);
        hnacc[i] = fmaf(hv, wn, hnacc[i]);
      }
    }
  }

  const float vbri = bri[a * H_ + n], vbzi = bzi[a * H_ + n], vbni = bni[a * H_ + n];
  const float vbrh = brh[a * H_ + n], vbzh = bzh[a * H_ + n], vbnh = bnh[a * H_ + n];

  #pragma unroll
  for (int i = 0; i < 4; ++i) {
    int b = b0 + bg * 4 + i;
    float hold = hprev[(size_t)(a * B_ + b) * H_ + n];
    float r  = sigm(racc[i] + vbri + vbrh);
    float z  = sigm(zacc[i] + vbzi + vbzh);
    float nn = tanh_f(xnacc[i] + vbni + r * (hnacc[i] + vbnh));
    float hnew = (1.f - z) * nn + z * hold;
    out[((size_t)(a * B_ + b) * S_ + s) * H_ + n] = hnew;
    hnext[(size_t)(a * B_ + b) * H_ + n] = hnew;
    if (s == S_ - 1) hlast[(size_t)(a * B_ + b) * H_ + n] = hnew;
  }
}

extern "C" void kernel_launch(void* const* d_in, const int* in_sizes, int n_in,
                              void* d_out, int out_size, void* d_ws, size_t ws_size,
                              hipStream_t stream)
{
  const float* x   = (const float*)d_in[0];
  const float* wri = (const float*)d_in[1];
  const float* wzi = (const float*)d_in[2];
  const float* wni = (const float*)d_in[3];
  const float* wrh = (const float*)d_in[4];
  const float* wzh = (const float*)d_in[5];
  const float* wnh = (const float*)d_in[6];
  const float* bri = (const float*)d_in[7];
  const float* bzi = (const float*)d_in[8];
  const float* bni = (const float*)d_in[9];
  const float* brh = (const float*)d_in[10];
  const float* bzh = (const float*)d_in[11];
  const float* bnh = (const float*)d_in[12];

  float* out   = (float*)d_out;                    // (A,B,S,H)
  float* hlast = out + (size_t)A_ * B_ * S_ * H_;  // (A,B,H)

  float* h0 = (float*)d_ws;
  float* h1 = h0 + (size_t)A_ * B_ * H_;

  hipMemsetAsync(h0, 0, (size_t)A_ * B_ * H_ * sizeof(float), stream);

  dim3 grid(16, 2, A_);
  for (int s = 0; s < S_; ++s) {
    const float* hp = (s & 1) ? h1 : h0;
    float*       hn = (s & 1) ? h0 : h1;
    gru_step<<<grid, 256, 0, stream>>>(x, wri, wzi, wni, wrh, wzh, wnh,
                                       bri, bzi, bni, brh, bzh, bnh,
                                       hp, hn, out, hlast, s);
  }
}

// Round 2
// 2649.039 us; speedup vs baseline: 4.7926x; 4.7926x over previous
//
#include <hip/hip_runtime.h>

#define A_ 8
#define B_ 64
#define S_ 128
#define E_ 512
#define H_ 512

typedef float f32x4 __attribute__((ext_vector_type(4)));
typedef short s16x8 __attribute__((ext_vector_type(8)));

__device__ __forceinline__ float sigm(float v)   { return 1.f / (1.f + __expf(-v)); }
__device__ __forceinline__ float tanh_f(float v) { return 2.f / (1.f + __expf(-2.f * v)) - 1.f; }

__device__ __forceinline__ unsigned short f2bf(float f) {
  unsigned u = __builtin_bit_cast(unsigned, f);
  u += 0x7fffu + ((u >> 16) & 1u);
  return (unsigned short)(u >> 16);
}
__device__ __forceinline__ float bf2f(unsigned short b) {
  return __builtin_bit_cast(float, ((unsigned)b) << 16);
}

union U2 { unsigned long long u[2]; s16x8 v; };
union PK { uint4 u; unsigned short h[8]; };

// ---------------------------------------------------------------------------
// Persistent GRU scan. 256 WGs: a = wg>>5 (8), slice = wg&31 (32).
// Each WG: 16 output cols (n0..n0+15) of all 3 gates, all 64 b-rows.
// 4 waves; wave w owns b-rows [w*16, w*16+16). MFMA 16x16x32 bf16.
// Weights live in LDS as pre-built B-fragments (96 KB).
// h state: bf16 ping-pong in ws, blocked [a][kb=64][row=64][8] for coalesced
// A-fragment loads. Cross-WG sync: per-a 32-flag release/acquire barrier.
// ---------------------------------------------------------------------------
__global__ __launch_bounds__(256, 1) void gru_persist(
    const float* __restrict__ x,
    const float* __restrict__ wri, const float* __restrict__ wzi, const float* __restrict__ wni,
    const float* __restrict__ wrh, const float* __restrict__ wzh, const float* __restrict__ wnh,
    const float* __restrict__ bri, const float* __restrict__ bzi, const float* __restrict__ bni,
    const float* __restrict__ brh, const float* __restrict__ bzh, const float* __restrict__ bnh,
    float* __restrict__ out, float* __restrict__ hlast,
    unsigned short* __restrict__ hbuf0, unsigned short* __restrict__ hbuf1,
    int* __restrict__ flags)
{
  __shared__ uint4 wflat[6144];   // [set(2)][gate(3)][kk(16)][lane(64)] = 96 KB

  const int wg    = blockIdx.x;
  const int a     = wg >> 5;
  const int slice = wg & 31;
  const int n0    = slice << 4;
  const int tid   = threadIdx.x;
  const int lane  = tid & 63;
  const int wid   = tid >> 6;
  const int l15   = lane & 15;
  const int l4    = lane >> 4;
  const int b0w   = wid << 4;

  // ---- build weight B-fragments in LDS (once) ----
  for (int idx = tid; idx < 6144; idx += 256) {
    int set  = idx / 3072;
    int rem  = idx - set * 3072;
    int gate = rem >> 10;
    int rem2 = rem & 1023;
    int kk   = rem2 >> 6;
    int l    = rem2 & 63;
    int c     = l & 15;
    int kbase = kk * 32 + (l >> 4) * 8;
    const float* W = (set == 0)
        ? (gate == 0 ? wri : gate == 1 ? wzi : wni)
        : (gate == 0 ? wrh : gate == 1 ? wzh : wnh);
    const float* wp = W + ((size_t)(a * 512 + kbase)) * 512 + n0 + c;
    PK pk;
#pragma unroll
    for (int j = 0; j < 8; ++j) pk.h[j] = f2bf(wp[(size_t)j * 512]);
    wflat[idx] = pk.u;
  }
  __syncthreads();

  const int nc = n0 + l15;   // this lane's output column
  const float vbri = bri[a * 512 + nc], vbzi = bzi[a * 512 + nc], vbni = bni[a * 512 + nc];
  const float vbrh = brh[a * 512 + nc], vbzh = bzh[a * 512 + nc], vbnh = bnh[a * 512 + nc];

  const float* xrow = x + (size_t)(a * 64 + b0w + l15) * 65536 + l4 * 8;
  const int hbase = ((a * 64 + l4) * 64 + b0w + l15) * 8;  // + kk*2048
  int* flagsA = flags + a * 64;

  const f32x4 zero4 = {0.f, 0.f, 0.f, 0.f};
  f32x4 aR, aZ, aXN, aHN;

  auto xpart = [&](int sv) {
    const float* xp = xrow + (size_t)sv * 512;
    aR = zero4; aZ = zero4; aXN = zero4;
#pragma unroll
    for (int kk = 0; kk < 16; ++kk) {
      float4 x0 = *reinterpret_cast<const float4*>(xp + kk * 32);
      float4 x1 = *reinterpret_cast<const float4*>(xp + kk * 32 + 4);
      union { s16x8 v; unsigned short h[8]; } af;
      af.h[0] = f2bf(x0.x); af.h[1] = f2bf(x0.y); af.h[2] = f2bf(x0.z); af.h[3] = f2bf(x0.w);
      af.h[4] = f2bf(x1.x); af.h[5] = f2bf(x1.y); af.h[6] = f2bf(x1.z); af.h[7] = f2bf(x1.w);
      s16x8 bR = __builtin_bit_cast(s16x8, wflat[(kk)      * 64 + lane]);
      s16x8 bZ = __builtin_bit_cast(s16x8, wflat[(16 + kk) * 64 + lane]);
      s16x8 bN = __builtin_bit_cast(s16x8, wflat[(32 + kk) * 64 + lane]);
      aR  = __builtin_amdgcn_mfma_f32_16x16x32_bf16(af.v, bR, aR, 0, 0, 0);
      aZ  = __builtin_amdgcn_mfma_f32_16x16x32_bf16(af.v, bZ, aZ, 0, 0, 0);
      aXN = __builtin_amdgcn_mfma_f32_16x16x32_bf16(af.v, bN, aXN, 0, 0, 0);
    }
  };

  auto hpart = [&](const unsigned short* hprev) {
    aHN = zero4;
#pragma unroll
    for (int kk = 0; kk < 16; ++kk) {
      unsigned long long* p = (unsigned long long*)(hprev + hbase + kk * 2048);
      U2 uu;
      uu.u[0] = __hip_atomic_load(p,     __ATOMIC_RELAXED, __HIP_MEMORY_SCOPE_AGENT);
      uu.u[1] = __hip_atomic_load(p + 1, __ATOMIC_RELAXED, __HIP_MEMORY_SCOPE_AGENT);
      s16x8 bR = __builtin_bit_cast(s16x8, wflat[(48 + kk) * 64 + lane]);
      s16x8 bZ = __builtin_bit_cast(s16x8, wflat[(64 + kk) * 64 + lane]);
      s16x8 bN = __builtin_bit_cast(s16x8, wflat[(80 + kk) * 64 + lane]);
      aR  = __builtin_amdgcn_mfma_f32_16x16x32_bf16(uu.v, bR, aR, 0, 0, 0);
      aZ  = __builtin_amdgcn_mfma_f32_16x16x32_bf16(uu.v, bZ, aZ, 0, 0, 0);
      aHN = __builtin_amdgcn_mfma_f32_16x16x32_bf16(uu.v, bN, aHN, 0, 0, 0);
    }
  };

  xpart(0);

  for (int s = 0; s < S_; ++s) {
    const unsigned short* hprev = (s & 1) ? hbuf0 : hbuf1;  // s=0 reads zeroed hbuf1
    unsigned short*       hcur  = (s & 1) ? hbuf1 : hbuf0;

    hpart(hprev);

    // epilogue: gate math + writes (C layout: col = lane&15, row = (lane>>4)*4 + i)
#pragma unroll
    for (int i = 0; i < 4; ++i) {
      int r = b0w + l4 * 4 + i;
      unsigned* hop = (unsigned*)(hprev + ((a * 64 + (nc >> 3)) * 64 + r) * 8 + (nc & 6));
      unsigned pair = __hip_atomic_load(hop, __ATOMIC_RELAXED, __HIP_MEMORY_SCOPE_AGENT);
      float hold = bf2f((nc & 1) ? (unsigned short)(pair >> 16) : (unsigned short)(pair & 0xffff));
      float rg = sigm(aR[i] + vbri + vbrh);
      float zg = sigm(aZ[i] + vbzi + vbzh);
      float ng = tanh_f(aXN[i] + vbni + rg * (aHN[i] + vbnh));
      float hnew = (1.f - zg) * ng + zg * hold;
      out[((size_t)(a * 64 + r) * 128 + s) * 512 + nc] = hnew;
      if (s == S_ - 1) hlast[(size_t)(a * 64 + r) * 512 + nc] = hnew;
      unsigned short nb = f2bf(hnew);
      unsigned other = __shfl_xor((unsigned)nb, 1);
      if ((lane & 1) == 0) {
        unsigned val = (unsigned)nb | (other << 16);
        __hip_atomic_store((unsigned*)(hcur + ((a * 64 + (nc >> 3)) * 64 + r) * 8 + (nc & 6)),
                           val, __ATOMIC_RELAXED, __HIP_MEMORY_SCOPE_AGENT);
      }
    }

    __syncthreads();
    if (tid == 0)
      __hip_atomic_store(flagsA + slice, s + 1, __ATOMIC_RELEASE, __HIP_MEMORY_SCOPE_AGENT);

    if (s < S_ - 1) {
      xpart(s + 1);  // no h dependency: overlaps the barrier
      const int target = s + 1;
      for (;;) {
        int v = __hip_atomic_load(flagsA + (lane & 31), __ATOMIC_ACQUIRE, __HIP_MEMORY_SCOPE_AGENT);
        if (__all(v >= target)) break;
        __builtin_amdgcn_s_sleep(1);
      }
    }
  }
}

// ---------------------------------------------------------------------------
// Fallback (round-1) per-step kernel, used only if ws_size is too small.
// ---------------------------------------------------------------------------
#define KT 128
__global__ __launch_bounds__(256) void gru_step(
    const float* __restrict__ x,
    const float* __restrict__ wri, const float* __restrict__ wzi, const float* __restrict__ wni,
    const float* __restrict__ wrh, const float* __restrict__ wzh, const float* __restrict__ wnh,
    const float* __restrict__ bri, const float* __restrict__ bzi, const float* __restrict__ bni,
    const float* __restrict__ brh, const float* __restrict__ bzh, const float* __restrict__ bnh,
    const float* __restrict__ hprev, float* __restrict__ hnext,
    float* __restrict__ out, float* __restrict__ hlast, int s)
{
  const int jn = blockIdx.x, jb = blockIdx.y, a = blockIdx.z;
  const int tid = threadIdx.x, tn = tid & 31, bg = tid >> 5;
  const int n = jn * 32 + tn, b0 = jb * 32;
  __shared__ float xt[32][KT];
  __shared__ float ht[32][KT];
  float racc[4] = {0,0,0,0}, zacc[4] = {0,0,0,0}, xnacc[4] = {0,0,0,0}, hnacc[4] = {0,0,0,0};
  for (int kt0 = 0; kt0 < E_; kt0 += KT) {
    __syncthreads();
#pragma unroll
    for (int t = 0; t < 4; ++t) {
      int idx = tid + t * 256, row = idx >> 5, c4 = idx & 31;
      reinterpret_cast<float4*>(&xt[row][0])[c4] =
          *(reinterpret_cast<const float4*>(x + (((size_t)(a*B_+b0+row)*S_+s)*E_+kt0)) + c4);
    }
    __syncthreads();
    size_t wb = (size_t)(a * E_ + kt0) * H_ + n;
#pragma unroll 4
    for (int k = 0; k < KT; ++k) {
      float wr = wri[wb+(size_t)k*H_], wz = wzi[wb+(size_t)k*H_], wn = wni[wb+(size_t)k*H_];
#pragma unroll
      for (int i = 0; i < 4; ++i) {
        float xv = xt[bg*4+i][k];
        racc[i]=fmaf(xv,wr,racc[i]); zacc[i]=fmaf(xv,wz,zacc[i]); xnacc[i]=fmaf(xv,wn,xnacc[i]);
      }
    }
  }
  for (int kt0 = 0; kt0 < H_; kt0 += KT) {
    __syncthreads();
#pragma unroll
    for (int t = 0; t < 4; ++t) {
      int idx = tid + t * 256, row = idx >> 5, c4 = idx & 31;
      reinterpret_cast<float4*>(&ht[row][0])[c4] =
          *(reinterpret_cast<const float4*>(hprev + ((size_t)(a*B_+b0+row)*H_+kt0)) + c4);
    }
    __syncthreads();
    size_t wb = (size_t)(a * H_ + kt0) * H_ + n;
#pragma unroll 4
    for (int k = 0; k < KT; ++k) {
      float wr = wrh[wb+(size_t)k*H_], wz = wzh[wb+(size_t)k*H_], wn = wnh[wb+(size_t)k*H_];
#pragma unroll
      for (int i = 0; i < 4; ++i) {
        float hv = ht[bg*4+i][k];
        racc[i]=fmaf(hv,wr,racc[i]); zacc[i]=fmaf(hv,wz,zacc[i]); hnacc[i]=fmaf(hv,wn,hnacc[i]);
      }
    }
  }
  const float vbri=bri[a*H_+n], vbzi=bzi[a*H_+n], vbni=bni[a*H_+n];
  const float vbrh=brh[a*H_+n], vbzh=bzh[a*H_+n], vbnh=bnh[a*H_+n];
#pragma unroll
  for (int i = 0; i < 4; ++i) {
    int b = b0 + bg * 4 + i;
    float hold = hprev[(size_t)(a*B_+b)*H_+n];
    float r = sigm(racc[i]+vbri+vbrh);
    float z = sigm(zacc[i]+vbzi+vbzh);
    float nn = tanh_f(xnacc[i]+vbni+r*(hnacc[i]+vbnh));
    float hnew = (1.f-z)*nn + z*hold;
    out[((size_t)(a*B_+b)*S_+s)*H_+n] = hnew;
    hnext[(size_t)(a*B_+b)*H_+n] = hnew;
    if (s == S_-1) hlast[(size_t)(a*B_+b)*H_+n] = hnew;
  }
}

extern "C" void kernel_launch(void* const* d_in, const int* in_sizes, int n_in,
                              void* d_out, int out_size, void* d_ws, size_t ws_size,
                              hipStream_t stream)
{
  const float* x   = (const float*)d_in[0];
  const float* wri = (const float*)d_in[1];
  const float* wzi = (const float*)d_in[2];
  const float* wni = (const float*)d_in[3];
  const float* wrh = (const float*)d_in[4];
  const float* wzh = (const float*)d_in[5];
  const float* wnh = (const float*)d_in[6];
  const float* bri = (const float*)d_in[7];
  const float* bzi = (const float*)d_in[8];
  const float* bni = (const float*)d_in[9];
  const float* brh = (const float*)d_in[10];
  const float* bzh = (const float*)d_in[11];
  const float* bnh = (const float*)d_in[12];

  float* out   = (float*)d_out;                    // (A,B,S,H)
  float* hlast = out + (size_t)A_ * B_ * S_ * H_;  // (A,B,H)

  const size_t HBUF = (size_t)A_ * 64 * 64 * 8;    // 262144 bf16 elems = 512 KB
  const size_t need = HBUF * 2 * sizeof(unsigned short) + 8 * 64 * sizeof(int);

  if (ws_size >= need) {
    unsigned short* hbuf0 = (unsigned short*)d_ws;
    unsigned short* hbuf1 = hbuf0 + HBUF;
    int* flags = (int*)((char*)d_ws + HBUF * 2 * sizeof(unsigned short));
    hipMemsetAsync(d_ws, 0, need, stream);
    gru_persist<<<256, 256, 0, stream>>>(x, wri, wzi, wni, wrh, wzh, wnh,
                                         bri, bzi, bni, brh, bzh, bnh,
                                         out, hlast, hbuf0, hbuf1, flags);
  } else {
    float* h0 = (float*)d_ws;
    float* h1 = h0 + (size_t)A_ * B_ * H_;
    hipMemsetAsync(h0, 0, (size_t)A_ * B_ * H_ * sizeof(float), stream);
    dim3 grid(16, 2, A_);
    for (int s = 0; s < S_; ++s) {
      const float* hp = (s & 1) ? h1 : h0;
      float*       hn = (s & 1) ? h0 : h1;
      gru_step<<<grid, 256, 0, stream>>>(x, wri, wzi, wni, wrh, wzh, wnh,
                                         bri, bzi, bni, brh, bzh, bnh,
                                         hp, hn, out, hlast, s);
    }
  }
}